// Round 7
// baseline (166.891 us; speedup 1.0000x reference)
//
#include <hip/hip_runtime.h>

// UpCaps fused, transposed lanes + packed-fp32 math + LDS x-tile.
// lane = a*8 + cg (cg = c/2); each lane holds votes for all 8 batches of its
// (a, c=2cg..2cg+1) as float2 (v2f) -> conv inner loop is v_pk_fma_f32.
// x is repacked into d_ws as xp[ci][iy][ixp][b] (padded), then each block
// stages its 15KB x-tile into LDS once (shared by 4 waves); conv x-reads are
// wave-uniform broadcast ds_read_b128 (no bank conflicts, short latency).
// Softmax over b is lane-local; squash reduces over a-lanes (xor 8,16,32);
// logit update reduces over cg-lanes (xor 1,2,4).
// Output through an LDS block transpose -> full-64B-line stores.
// Shapes: x(8,16,96,96), w(5,5,16,8,16), out(8,16,192,192).
typedef float v2f __attribute__((ext_vector_type(2)));

#define XH 96
#define XW 96
#define CIN 16
#define NA 8
#define NC 16
#define OH 192
#define OW 192
#define WP 102                        // padded width: ix in [-1,100] -> ixp 0..101
#define PADN (CIN * XH * WP * 8)      // 1,253,376 floats

__global__ __launch_bounds__(256) void pad_x(const float* __restrict__ x,
                                             float* __restrict__ xp) {
  int idx = blockIdx.x * 256 + threadIdx.x;
  if (idx >= PADN) return;
  int b   = idx & 7;
  int t   = idx >> 3;
  int ixp = t % WP;
  int t2  = t / WP;
  int iy  = t2 % XH;
  int ci  = t2 / XH;
  int ix  = ixp - 1;
  float v = 0.f;
  if (ix >= 0 && ix < XW)
    v = x[((b * CIN + ci) * XH + iy) * XW + ix];
  xp[idx] = v;
}

// routes two pixels interleaved; va/vb = votes[b] (c-pair) for this lane's
// (a, 2cg..2cg+1). On exit qa/qb hold final squashed preds (c-pair).
__device__ __forceinline__ void route_pair(
    const v2f (&va)[8], const v2f (&vb)[8], int R, v2f& qa, v2f& qb)
{
  float lga[8], lgb[8];
#pragma unroll
  for (int b = 0; b < 8; ++b) { lga[b] = 0.f; lgb[b] = 0.f; }
#pragma unroll 1
  for (int r = 0; r < R; ++r) {
    float sla[8], slb[8];
    if (r == 0) {
#pragma unroll
      for (int b = 0; b < 8; ++b) { sla[b] = 0.125f; slb[b] = 0.125f; }
    } else {
      // softmax over batch: fully lane-local
      float ma = lga[0], mb = lgb[0];
#pragma unroll
      for (int b = 1; b < 8; ++b) { ma = fmaxf(ma, lga[b]); mb = fmaxf(mb, lgb[b]); }
      float sa = 0.f, sb = 0.f;
#pragma unroll
      for (int b = 0; b < 8; ++b) {
        sla[b] = __expf(lga[b] - ma); sa += sla[b];
        slb[b] = __expf(lgb[b] - mb); sb += slb[b];
      }
      const float ira = __builtin_amdgcn_rcpf(sa);   // sa >= 1 > 0
      const float irb = __builtin_amdgcn_rcpf(sb);
#pragma unroll
      for (int b = 0; b < 8; ++b) { sla[b] *= ira; slb[b] *= irb; }
    }

    // preds = sum_b votes * sl : lane-local pk-FMA chain
    qa = (v2f){0.f, 0.f};  qb = (v2f){0.f, 0.f};
#pragma unroll
    for (int b = 0; b < 8; ++b) {
      qa = __builtin_elementwise_fma((v2f){sla[b], sla[b]}, va[b], qa);
      qb = __builtin_elementwise_fma((v2f){slb[b], slb[b]}, vb[b], qb);
    }

    // squash: norm^2 over atoms = reduce over a-lanes (bits 3..5)
    {
      float na0 = qa.x * qa.x, na1 = qa.y * qa.y;
      float nb0 = qb.x * qb.x, nb1 = qb.y * qb.y;
      na0 += __shfl_xor(na0, 8);  na1 += __shfl_xor(na1, 8);
      nb0 += __shfl_xor(nb0, 8);  nb1 += __shfl_xor(nb1, 8);
      na0 += __shfl_xor(na0, 16); na1 += __shfl_xor(na1, 16);
      nb0 += __shfl_xor(nb0, 16); nb1 += __shfl_xor(nb1, 16);
      na0 += __shfl_xor(na0, 32); na1 += __shfl_xor(na1, 32);
      nb0 += __shfl_xor(nb0, 32); nb1 += __shfl_xor(nb1, 32);
      qa.x *= sqrtf(na0) * __builtin_amdgcn_rcpf(1.f + na0);  // sqrt(n)/(1+n)
      qa.y *= sqrtf(na1) * __builtin_amdgcn_rcpf(1.f + na1);
      qb.x *= sqrtf(nb0) * __builtin_amdgcn_rcpf(1.f + nb0);
      qb.y *= sqrtf(nb1) * __builtin_amdgcn_rcpf(1.f + nb1);
    }

    // logits = softmaxed + sum_c votes*preds (reduce over cg-lanes, bits 0..2)
    if (r + 1 < R) {
#pragma unroll
      for (int b = 0; b < 8; ++b) {
        float da = fmaf(va[b].x, qa.x, va[b].y * qa.y);
        float db = fmaf(vb[b].x, qb.x, vb[b].y * qb.y);
        da += __shfl_xor(da, 1);  db += __shfl_xor(db, 1);
        da += __shfl_xor(da, 2);  db += __shfl_xor(db, 2);
        da += __shfl_xor(da, 4);  db += __shfl_xor(db, 4);
        lga[b] = sla[b] + da;     lgb[b] = slb[b] + db;
      }
    }
  }
}

__global__ __launch_bounds__(256, 4) void upcaps_tr2(
    const float* __restrict__ xp,    // padded [ci][iy][ixp][b]
    const float* __restrict__ wts,
    const int* __restrict__ nroutes,
    float* __restrict__ out)
{
  __shared__ float smem[3840];          // x-tile 15KB, later reused as out-stage

  const int lane = threadIdx.x & 63;
  const int wid  = threadIdx.x >> 6;
  const int tile = blockIdx.x;          // 2304 blocks, 16 px each
  const int oy   = tile / 12;
  const int xg   = (tile - oy * 12) * 16;   // 64B-line aligned
  const int xgh  = xg >> 1;
  const int kyBase = oy & 1;            // valid ky = kyBase + 2*kyI

  // -------- stage x-tile: smem[((ci*3+kyI)*10+col)*8 + b] --------
  for (int s = threadIdx.x; s < 480; s += 256) {
    const int col = s % 10;
    const int t   = s / 10;
    const int kyI = t % 3;
    const int ci  = t / 3;
    const int ky  = kyBase + 2 * kyI;
    const int py  = oy - 2 + ky;
    if (ky <= 4 && py >= 0 && py <= 2 * XH - 2) {
      const int iy = py >> 1;
      const float4* src = (const float4*)(xp + ((ci * XH + iy) * WP + (xgh + col)) * 8);
      float4* dst = (float4*)&smem[((ci * 3 + kyI) * 10 + col) * 8];
      dst[0] = src[0];
      dst[1] = src[1];
    }
  }
  __syncthreads();

  const int pxb  = (wid & 1) + ((wid >> 1) << 3);   // wave px: pxb + 2j
  const int a    = lane >> 3;
  const int cg   = lane & 7;
  const int e    = pxb & 1;                          // ox parity (xg even)
  const int wcol0 = (wid & 1) + (wid >> 1) * 4;      // LDS col base: 0,1,4,5
  const bool use_t2 = (e == 0);
  const int wlane = a * NC + cg * 2;

  v2f acc[4][8];
#pragma unroll
  for (int j = 0; j < 4; ++j)
#pragma unroll
    for (int b = 0; b < 8; ++b) acc[j][b] = (v2f){0.f, 0.f};

  for (int kyI = 0; kyI < 3; ++kyI) {
    const int ky = kyBase + 2 * kyI;
    const int py = oy - 2 + ky;
    if (ky > 4 || py < 0 || py > 2 * XH - 2) continue;   // wave-uniform
    const float* xbase = &smem[(kyI * 10 + wcol0) * 8];  // + ci*240 + ir*8
    const float* wk = wts + (ky * 5 + e) * (CIN * NA * NC) + wlane;
#pragma unroll 2
    for (int ci = 0; ci < CIN; ++ci) {
      const v2f cw0 = *(const v2f*)(wk + ci * (NA * NC));
      const v2f cw1 = *(const v2f*)(wk + 2 * (CIN * NA * NC) + ci * (NA * NC));
      v2f cw2 = (v2f){0.f, 0.f};
      if (use_t2) cw2 = *(const v2f*)(wk + 4 * (CIN * NA * NC) + ci * (NA * NC));
      const float* xci = xbase + ci * 240;
#pragma unroll
      for (int ir = 0; ir < 6; ++ir) {
        if (ir == 5 && !use_t2) continue;              // odd parity: ir<=4
        const float4 xlo = *(const float4*)(xci + ir * 8);      // uniform bcast
        const float4 xhi = *(const float4*)(xci + ir * 8 + 4);
        const float xv[8] = {xlo.x, xlo.y, xlo.z, xlo.w,
                             xhi.x, xhi.y, xhi.z, xhi.w};
        if (ir <= 3) {                                 // tap t=0, j=ir
#pragma unroll
          for (int b = 0; b < 8; ++b) {
            const v2f xs = (v2f){xv[b], xv[b]};
            acc[ir][b] = __builtin_elementwise_fma(xs, cw0, acc[ir][b]);
          }
        }
        if (ir >= 1 && ir <= 4) {                      // tap t=1, j=ir-1
#pragma unroll
          for (int b = 0; b < 8; ++b) {
            const v2f xs = (v2f){xv[b], xv[b]};
            acc[ir - 1][b] = __builtin_elementwise_fma(xs, cw1, acc[ir - 1][b]);
          }
        }
        if (ir >= 2 && use_t2) {                       // tap t=2, j=ir-2
#pragma unroll
          for (int b = 0; b < 8; ++b) {
            const v2f xs = (v2f){xv[b], xv[b]};
            acc[ir - 2][b] = __builtin_elementwise_fma(xs, cw2, acc[ir - 2][b]);
          }
        }
      }
    }
  }

  // -------- routing (2 interleaved pairs) --------
  const int R = nroutes[0];
  v2f q0, q1, q2, q3;
  route_pair(acc[0], acc[1], R, q0, q1);
  route_pair(acc[2], acc[3], R, q2, q3);

  // -------- stage results to LDS: [pxi][a*16+c] (smem reuse, barriered) ----
  __syncthreads();
  float* lds_out = smem;
  const int lbase = a * NC + cg * 2;
  *(v2f*)&lds_out[(pxb    ) * 128 + lbase] = q0;
  *(v2f*)&lds_out[(pxb + 2) * 128 + lbase] = q1;
  *(v2f*)&lds_out[(pxb + 4) * 128 + lbase] = q2;
  *(v2f*)&lds_out[(pxb + 6) * 128 + lbase] = q3;
  __syncthreads();

  // -------- coalesced output: thread -> (row r = a*16+c, half h) --------
  const int t = threadIdx.x;
  const int r = t >> 1, h = t & 1;
  float4 f0, f1;
  f0.x = lds_out[(h * 8 + 0) * 128 + r];
  f0.y = lds_out[(h * 8 + 1) * 128 + r];
  f0.z = lds_out[(h * 8 + 2) * 128 + r];
  f0.w = lds_out[(h * 8 + 3) * 128 + r];
  f1.x = lds_out[(h * 8 + 4) * 128 + r];
  f1.y = lds_out[(h * 8 + 5) * 128 + r];
  f1.z = lds_out[(h * 8 + 6) * 128 + r];
  f1.w = lds_out[(h * 8 + 7) * 128 + r];
  float* op = out + r * (OH * OW) + oy * OW + xg + h * 8;
  *(float4*)op       = f0;
  *(float4*)(op + 4) = f1;
}

extern "C" void kernel_launch(void* const* d_in, const int* in_sizes, int n_in,
                              void* d_out, int out_size, void* d_ws, size_t ws_size,
                              hipStream_t stream) {
  const float* x   = (const float*)d_in[0];
  const float* w   = (const float*)d_in[1];
  const int*   nr  = (const int*)d_in[2];
  float*       out = (float*)d_out;
  float*       xp  = (float*)d_ws;       // needs PADN*4 = 5,013,504 bytes

  pad_x<<<(PADN + 255) / 256, 256, 0, stream>>>(x, xp);
  upcaps_tr2<<<(OH * OW) / 16, 256, 0, stream>>>(xp, w, nr, out);
}

// Round 8
// 144.047 us; speedup vs baseline: 1.1586x; 1.1586x over previous
//
#include <hip/hip_runtime.h>

// UpCaps fused, transposed lanes + packed-fp32 math (R6 memory structure).
// lane = a*8 + cg (cg = c/2); each lane holds votes for all 8 batches of its
// (a, c=2cg..2cg+1) as float2 (v2f) -> conv inner loop is v_pk_fma_f32.
// x repacked into d_ws as xp[ci][iy][ixp][b] (padded) so conv x-reads are
// wave-uniform 32B loads, no edge branches. Softmax over b lane-local;
// squash reduces over a-lanes (xor 8,16,32); logit update over cg-lanes
// (xor 1,2,4). Output via 8KB LDS transpose -> full-64B-line stores.
// __launch_bounds__(256,3): VGPR cap ~168 > ~115 peak live -> NO spills
// (R7's (256,4) cap of 128 caused 110MB of scratch traffic).
// Shapes: x(8,16,96,96), w(5,5,16,8,16), out(8,16,192,192).
typedef float v2f __attribute__((ext_vector_type(2)));

#define XH 96
#define XW 96
#define CIN 16
#define NA 8
#define NC 16
#define OH 192
#define OW 192
#define WP 102                        // padded width: ix in [-1,100] -> ixp 0..101
#define PADN (CIN * XH * WP * 8)      // 1,253,376 floats

__global__ __launch_bounds__(256) void pad_x(const float* __restrict__ x,
                                             float* __restrict__ xp) {
  int idx = blockIdx.x * 256 + threadIdx.x;
  if (idx >= PADN) return;
  int b   = idx & 7;
  int t   = idx >> 3;
  int ixp = t % WP;
  int t2  = t / WP;
  int iy  = t2 % XH;
  int ci  = t2 / XH;
  int ix  = ixp - 1;
  float v = 0.f;
  if (ix >= 0 && ix < XW)
    v = x[((b * CIN + ci) * XH + iy) * XW + ix];
  xp[idx] = v;
}

// routes two pixels interleaved; va/vb = votes[b] (c-pair) for this lane's
// (a, 2cg..2cg+1). On exit qa/qb hold final squashed preds (c-pair).
__device__ __forceinline__ void route_pair(
    const v2f (&va)[8], const v2f (&vb)[8], int R, v2f& qa, v2f& qb)
{
  float lga[8], lgb[8];
#pragma unroll
  for (int b = 0; b < 8; ++b) { lga[b] = 0.f; lgb[b] = 0.f; }
#pragma unroll 1
  for (int r = 0; r < R; ++r) {
    float sla[8], slb[8];
    if (r == 0) {
#pragma unroll
      for (int b = 0; b < 8; ++b) { sla[b] = 0.125f; slb[b] = 0.125f; }
    } else {
      // softmax over batch: fully lane-local
      float ma = lga[0], mb = lgb[0];
#pragma unroll
      for (int b = 1; b < 8; ++b) { ma = fmaxf(ma, lga[b]); mb = fmaxf(mb, lgb[b]); }
      float sa = 0.f, sb = 0.f;
#pragma unroll
      for (int b = 0; b < 8; ++b) {
        sla[b] = __expf(lga[b] - ma); sa += sla[b];
        slb[b] = __expf(lgb[b] - mb); sb += slb[b];
      }
      const float ira = __builtin_amdgcn_rcpf(sa);   // sa >= 1 > 0
      const float irb = __builtin_amdgcn_rcpf(sb);
#pragma unroll
      for (int b = 0; b < 8; ++b) { sla[b] *= ira; slb[b] *= irb; }
    }

    // preds = sum_b votes * sl : lane-local pk-FMA chain
    qa = (v2f){0.f, 0.f};  qb = (v2f){0.f, 0.f};
#pragma unroll
    for (int b = 0; b < 8; ++b) {
      qa = __builtin_elementwise_fma((v2f){sla[b], sla[b]}, va[b], qa);
      qb = __builtin_elementwise_fma((v2f){slb[b], slb[b]}, vb[b], qb);
    }

    // squash: norm^2 over atoms = reduce over a-lanes (bits 3..5)
    {
      float na0 = qa.x * qa.x, na1 = qa.y * qa.y;
      float nb0 = qb.x * qb.x, nb1 = qb.y * qb.y;
      na0 += __shfl_xor(na0, 8);  na1 += __shfl_xor(na1, 8);
      nb0 += __shfl_xor(nb0, 8);  nb1 += __shfl_xor(nb1, 8);
      na0 += __shfl_xor(na0, 16); na1 += __shfl_xor(na1, 16);
      nb0 += __shfl_xor(nb0, 16); nb1 += __shfl_xor(nb1, 16);
      na0 += __shfl_xor(na0, 32); na1 += __shfl_xor(na1, 32);
      nb0 += __shfl_xor(nb0, 32); nb1 += __shfl_xor(nb1, 32);
      qa.x *= sqrtf(na0) * __builtin_amdgcn_rcpf(1.f + na0);  // sqrt(n)/(1+n)
      qa.y *= sqrtf(na1) * __builtin_amdgcn_rcpf(1.f + na1);
      qb.x *= sqrtf(nb0) * __builtin_amdgcn_rcpf(1.f + nb0);
      qb.y *= sqrtf(nb1) * __builtin_amdgcn_rcpf(1.f + nb1);
    }

    // logits = softmaxed + sum_c votes*preds (reduce over cg-lanes, bits 0..2)
    if (r + 1 < R) {
#pragma unroll
      for (int b = 0; b < 8; ++b) {
        float da = fmaf(va[b].x, qa.x, va[b].y * qa.y);
        float db = fmaf(vb[b].x, qb.x, vb[b].y * qb.y);
        da += __shfl_xor(da, 1);  db += __shfl_xor(db, 1);
        da += __shfl_xor(da, 2);  db += __shfl_xor(db, 2);
        da += __shfl_xor(da, 4);  db += __shfl_xor(db, 4);
        lga[b] = sla[b] + da;     lgb[b] = slb[b] + db;
      }
    }
  }
}

__global__ __launch_bounds__(256, 3) void upcaps_tr3(
    const float* __restrict__ xp,    // padded [ci][iy][ixp][b]
    const float* __restrict__ wts,
    const int* __restrict__ nroutes,
    float* __restrict__ out)
{
  __shared__ float lds_out[16 * 128];   // 8KB: [pxi][a*16+c]

  const int lane = threadIdx.x & 63;
  const int wid  = threadIdx.x >> 6;
  const int tile = blockIdx.x;          // 2304 blocks, 16 px each
  const int oy   = tile / 12;
  const int xg   = (tile - oy * 12) * 16;            // 64B-line aligned
  const int pxb  = (wid & 1) + ((wid >> 1) << 3);    // wave px: pxb + 2j
  const int oxw  = xg + pxb;
  const int a    = lane >> 3;
  const int cg   = lane & 7;
  const int e    = oxw & 1;
  // conv input col: ix = ixb + t + j,  t,j in [0,2]x[0,3]
  const int ixp0 = __builtin_amdgcn_readfirstlane(((oxw - 2 + e) >> 1) + 1);
  const bool use_t2 = (__builtin_amdgcn_readfirstlane(e) == 0);
  const int wlane = a * NC + cg * 2;    // per-lane float offset into w[..][a][c]

  v2f acc[4][8];
#pragma unroll
  for (int j = 0; j < 4; ++j)
#pragma unroll
    for (int b = 0; b < 8; ++b) acc[j][b] = (v2f){0.f, 0.f};

  for (int ky = 0; ky < 5; ++ky) {
    const int py = oy - 2 + ky;
    if (py < 0 || py > 2 * XH - 2 || (py & 1)) continue;   // wave-uniform
    const int iy = py >> 1;
    const float* wk = wts + (ky * 5 + e) * (CIN * NA * NC) + wlane;
#pragma unroll 2
    for (int ci = 0; ci < CIN; ++ci) {
      const float* xrow = xp + ((ci * XH + iy) * WP + ixp0) * 8;  // uniform
      const v2f cw0 = *(const v2f*)(wk + ci * (NA * NC));
      const v2f cw1 = *(const v2f*)(wk + 2 * (CIN * NA * NC) + ci * (NA * NC));
      v2f cw2 = (v2f){0.f, 0.f};
      if (use_t2) cw2 = *(const v2f*)(wk + 4 * (CIN * NA * NC) + ci * (NA * NC));
#pragma unroll
      for (int ir = 0; ir < 6; ++ir) {
        if (ir == 5 && !use_t2) continue;              // odd parity: ir<=4
        const float4 xlo = *(const float4*)(xrow + ir * 8);      // uniform
        const float4 xhi = *(const float4*)(xrow + ir * 8 + 4);
        const float xv[8] = {xlo.x, xlo.y, xlo.z, xlo.w,
                             xhi.x, xhi.y, xhi.z, xhi.w};
        if (ir <= 3) {                                 // tap t=0, j=ir
#pragma unroll
          for (int b = 0; b < 8; ++b) {
            const v2f xs = (v2f){xv[b], xv[b]};
            acc[ir][b] = __builtin_elementwise_fma(xs, cw0, acc[ir][b]);
          }
        }
        if (ir >= 1 && ir <= 4) {                      // tap t=1, j=ir-1
#pragma unroll
          for (int b = 0; b < 8; ++b) {
            const v2f xs = (v2f){xv[b], xv[b]};
            acc[ir - 1][b] = __builtin_elementwise_fma(xs, cw1, acc[ir - 1][b]);
          }
        }
        if (ir >= 2 && use_t2) {                       // tap t=2, j=ir-2
#pragma unroll
          for (int b = 0; b < 8; ++b) {
            const v2f xs = (v2f){xv[b], xv[b]};
            acc[ir - 2][b] = __builtin_elementwise_fma(xs, cw2, acc[ir - 2][b]);
          }
        }
      }
    }
  }

  // -------- routing (2 interleaved pairs) --------
  const int R = nroutes[0];
  v2f q0, q1, q2, q3;
  route_pair(acc[0], acc[1], R, q0, q1);
  route_pair(acc[2], acc[3], R, q2, q3);

  // -------- stage results to LDS: [pxi][a*16+c] --------
  const int lbase = a * NC + cg * 2;
  *(v2f*)&lds_out[(pxb    ) * 128 + lbase] = q0;
  *(v2f*)&lds_out[(pxb + 2) * 128 + lbase] = q1;
  *(v2f*)&lds_out[(pxb + 4) * 128 + lbase] = q2;
  *(v2f*)&lds_out[(pxb + 6) * 128 + lbase] = q3;
  __syncthreads();

  // -------- coalesced output: thread -> (row r = a*16+c, half h) --------
  const int t = threadIdx.x;
  const int r = t >> 1, h = t & 1;
  float4 f0, f1;
  f0.x = lds_out[(h * 8 + 0) * 128 + r];
  f0.y = lds_out[(h * 8 + 1) * 128 + r];
  f0.z = lds_out[(h * 8 + 2) * 128 + r];
  f0.w = lds_out[(h * 8 + 3) * 128 + r];
  f1.x = lds_out[(h * 8 + 4) * 128 + r];
  f1.y = lds_out[(h * 8 + 5) * 128 + r];
  f1.z = lds_out[(h * 8 + 6) * 128 + r];
  f1.w = lds_out[(h * 8 + 7) * 128 + r];
  float* op = out + r * (OH * OW) + oy * OW + xg + h * 8;
  *(float4*)op       = f0;
  *(float4*)(op + 4) = f1;
}

extern "C" void kernel_launch(void* const* d_in, const int* in_sizes, int n_in,
                              void* d_out, int out_size, void* d_ws, size_t ws_size,
                              hipStream_t stream) {
  const float* x   = (const float*)d_in[0];
  const float* w   = (const float*)d_in[1];
  const int*   nr  = (const int*)d_in[2];
  float*       out = (float*)d_out;
  float*       xp  = (float*)d_ws;       // needs PADN*4 = 5,013,504 bytes

  pad_x<<<(PADN + 255) / 256, 256, 0, stream>>>(x, xp);
  upcaps_tr3<<<(OH * OW) / 16, 256, 0, stream>>>(xp, w, nr, out);
}